// Round 5
// baseline (247.718 us; speedup 1.0000x reference)
//
#include <hip/hip_runtime.h>
#include <hip/hip_bf16.h>
#include <stdint.h>

// ResonanceAttention on MI355X (gfx950) — round 5.
// R4 post-mortem: flash was latency-bound (MfmaUtil 13%). Root cause: per-tile
// mask global_loads sit BEHIND the next-tile glds16 DMAs in the vmcnt FIFO, so
// waiting for mask forces the prefetch DMA to drain mid-tile => overlap defeated.
// R5: mask row staged to LDS once (k-loop has NO vmem except prefetch DMA);
// softmax in exp2 domain (log2e folded into Q projection scale, entropy *ln2).
// Pipeline: cvt5 -> gemm_qkv (fused Q/K/Vt) -> flash_attn -> gemm_out_bf.
// Blend loop folds to scale C=0.8509655 iff avg_entropy >= 0.2 (device-computed).

#define PRIME_SCALE 0.047245559126654356f  // 1/sqrt(7*64)
#define LOG2E       1.4426950408889634f
#define LN2         0.6931471805599453f
#define QSCALE      (PRIME_SCALE * LOG2E)  // Q pre-scaled so softmax uses exp2
#define BLEND_C     0.85096556f            // closed form of the MAX_ITERS recurrence

typedef __attribute__((ext_vector_type(8))) short short8;
typedef __attribute__((ext_vector_type(4))) float f32x4;

__device__ __forceinline__ unsigned short f2bf(float x) {
    union { float f; unsigned int u; } v; v.f = x;
    unsigned int r = (v.u + 0x7fffu + ((v.u >> 16) & 1u)) >> 16;  // RNE
    return (unsigned short)r;
}

// async global->LDS, 16B per lane; LDS dest = wave-uniform base + lane*16 [m97]
__device__ __forceinline__ void glds16(const unsigned short* g, unsigned short* l) {
    __builtin_amdgcn_global_load_lds((const __attribute__((address_space(1))) unsigned int*)g,
                                     (__attribute__((address_space(3))) unsigned int*)l,
                                     16, 0, 0);
}
__device__ __forceinline__ void glds16i(const int* g, int* l) {
    __builtin_amdgcn_global_load_lds((const __attribute__((address_space(1))) unsigned int*)g,
                                     (__attribute__((address_space(3))) unsigned int*)l,
                                     16, 0, 0);
}

__global__ void zero_ent(float* p) { p[0] = 0.f; }

__global__ void zero_out_f32(float* p, int n) {
    int i = blockIdx.x * 256 + threadIdx.x;
    if (i < n) p[i] = 0.f;
}

// ---------------------------------------------------------------------------
// cvt5: fp32 -> bf16 for hs (4M elems) + qw/kw/vw/ow (1M each). Zeros entp.
// ---------------------------------------------------------------------------
__global__ __launch_bounds__(256) void cvt5(
    const float* __restrict__ s0, const float* __restrict__ s1, const float* __restrict__ s2,
    const float* __restrict__ s3, const float* __restrict__ s4,
    unsigned short* __restrict__ d0, unsigned short* __restrict__ d1, unsigned short* __restrict__ d2,
    unsigned short* __restrict__ d3, unsigned short* __restrict__ d4, float* entp)
{
    if (blockIdx.x == 0 && threadIdx.x == 0) entp[0] = 0.f;
    unsigned int i = blockIdx.x * 256 + threadIdx.x;   // float4 group index, total 2^21
    const float* s; unsigned short* d; unsigned int off;
    if (i < (1u << 20)) { s = s0; d = d0; off = i; }
    else {
        unsigned int j = i - (1u << 20);
        unsigned int sel = j >> 18; off = j & 0x3FFFFu;
        s = sel == 0 ? s1 : sel == 1 ? s2 : sel == 2 ? s3 : s4;
        d = sel == 0 ? d1 : sel == 1 ? d2 : sel == 2 ? d3 : d4;
    }
    float4 v = ((const float4*)s)[off];
    ushort4 p; p.x = f2bf(v.x); p.y = f2bf(v.y); p.z = f2bf(v.z); p.w = f2bf(v.w);
    ((ushort4*)d)[off] = p;
}

// ---------------------------------------------------------------------------
// Fused Q/K/Vt GEMM, bf16 in -> bf16 out, global_load_lds staging (m97 structure).
// 768 blocks: op0=Q (hs@qw.T+qb)*QSCALE (log2-domain), op1=K, op2=Vt (operand swap).
// ---------------------------------------------------------------------------
__global__ __launch_bounds__(256) void gemm_qkv(
    const unsigned short* __restrict__ hsb,
    const unsigned short* __restrict__ qwb, const unsigned short* __restrict__ kwb,
    const unsigned short* __restrict__ vwb,
    const float* __restrict__ qb, const float* __restrict__ kb, const float* __restrict__ vb,
    unsigned short* __restrict__ Qo, unsigned short* __restrict__ Ko, unsigned short* __restrict__ Vto)
{
    const int bid = blockIdx.x;
    const int op = bid >> 8, local = bid & 255;
    const unsigned short *A, *B; const float* bias; unsigned short* C;
    int m0, n0, ldc, biasRow; float scale;
    if (op == 0)      { A = hsb; B = qwb; bias = qb; C = Qo;  m0 = (local >> 3) * 128; n0 = (local & 7) * 128;  ldc = 1024; biasRow = 0; scale = QSCALE; }
    else if (op == 1) { A = hsb; B = kwb; bias = kb; C = Ko;  m0 = (local >> 3) * 128; n0 = (local & 7) * 128;  ldc = 1024; biasRow = 0; scale = 1.f; }
    else              { A = vwb; B = hsb; bias = vb; C = Vto; m0 = (local >> 5) * 128; n0 = (local & 31) * 128; ldc = 4096; biasRow = 1; scale = 1.f; }

    __shared__ unsigned short As[128 * 32];
    __shared__ unsigned short Bs[128 * 32];
    const int t = threadIdx.x, lane = t & 63, w = t >> 6;
    const int quad = lane >> 4, l15 = lane & 15;
    const int wr = (w >> 1) * 64, wc = (w & 1) * 64;
    const int srow = lane >> 2, scol = (lane & 3) * 8;

    f32x4 acc[4][4];
#pragma unroll
    for (int i = 0; i < 4; ++i)
#pragma unroll
        for (int j = 0; j < 4; ++j) acc[i][j] = (f32x4){0.f, 0.f, 0.f, 0.f};

    for (int kk = 0; kk < 32; ++kk) {
        const int k0 = kk * 32;
#pragma unroll
        for (int j = 0; j < 2; ++j) {
            int row = (w * 2 + j) * 16 + srow;
            glds16(&A[(size_t)(m0 + row) * 1024 + k0 + scol], &As[(w * 2 + j) * 512]);
            glds16(&B[(size_t)(n0 + row) * 1024 + k0 + scol], &Bs[(w * 2 + j) * 512]);
        }
        __syncthreads();
        short8 af[4], bf[4];
#pragma unroll
        for (int mt = 0; mt < 4; ++mt) af[mt] = *(const short8*)&As[(wr + mt * 16 + l15) * 32 + quad * 8];
#pragma unroll
        for (int nt = 0; nt < 4; ++nt) bf[nt] = *(const short8*)&Bs[(wc + nt * 16 + l15) * 32 + quad * 8];
#pragma unroll
        for (int mt = 0; mt < 4; ++mt)
#pragma unroll
            for (int nt = 0; nt < 4; ++nt)
                acc[mt][nt] = __builtin_amdgcn_mfma_f32_16x16x32_bf16(af[mt], bf[nt], acc[mt][nt], 0, 0, 0);
        __syncthreads();
    }
#pragma unroll
    for (int mt = 0; mt < 4; ++mt) {
#pragma unroll
        for (int nt = 0; nt < 4; ++nt) {
            int n = n0 + wc + nt * 16 + l15;
#pragma unroll
            for (int r = 0; r < 4; ++r) {
                int m = m0 + wr + mt * 16 + quad * 4 + r;
                float bval = biasRow ? bias[m] : bias[n];
                C[(size_t)m * ldc + n] = f2bf((acc[mt][nt][r] + bval) * scale);
            }
        }
    }
}

// ---------------------------------------------------------------------------
// Flash attention r5: 128 q-rows/block (32/wave), glds16 K/V staging w/ global-
// side XOR swizzle, double-buffered, ONE barrier/tile. Mask row staged in LDS
// once => k-loop has zero VMEM besides prefetch DMA (vmcnt FIFO stays clean).
// Softmax in exp2 domain (Q pre-scaled by log2e); entropy = ln2*(log2 l - T2/l).
// ---------------------------------------------------------------------------
__global__ __launch_bounds__(256, 2) void flash_attn(
    const unsigned short* __restrict__ Q,
    const unsigned short* __restrict__ K,
    const unsigned short* __restrict__ Vt,
    const int* __restrict__ mask,
    unsigned short* __restrict__ O,
    float* __restrict__ entp)
{
    const int qt = blockIdx.x;          // 0..15, 128 q-rows each
    const int bh = blockIdx.y;          // 0..31
    const int b = bh >> 4, h = bh & 15;
    const int t = threadIdx.x, lane = t & 63, w = t >> 6;
    const int quad = lane >> 4, l15 = lane & 15;
    const int r8 = lane >> 3, ch8 = lane & 7;   // staging row-in-8 / chunk

    __shared__ unsigned short Qs[128 * 72];      // Q staged once; reused as Ps
    __shared__ unsigned short Ks[2][64 * 64];    // [k-row][d], chunk swizzled by row&7
    __shared__ unsigned short Vs[2][64 * 64];    // [d-row][k], chunk swizzled by row&7
    __shared__ int maskLds[2048];                // whole mask row for batch b

    const int* maskb = mask + b * 2048;
    // stage mask row once: 8 chunks x 256 ints, wave w does chunks {w, w+4}
#pragma unroll
    for (int i = 0; i < 2; ++i) {
        int c = w + i * 4;
        glds16i(&maskb[c * 256 + (lane << 2)], &maskLds[c * 256]);
    }
    // issue tile-0 K/V DMA (wave w stages rows w*16..w*16+15; 8 rows per glds16)
    {
        const int row0 = w * 16;
#pragma unroll
        for (int i = 0; i < 2; ++i) {
            int row = row0 + i * 8 + r8;
            int c = ch8 ^ (row & 7);           // global-side swizzle, same 128B lines
            glds16(&K[(size_t)(b * 2048 + row) * 1024 + h * 64 + c * 8], &Ks[0][(row0 + i * 8) * 64]);
            glds16(&Vt[(size_t)(h * 64 + row) * 4096 + b * 2048 + c * 8], &Vs[0][(row0 + i * 8) * 64]);
        }
    }
    // stage Q tile (once)
#pragma unroll
    for (int i = 0; i < 4; ++i) {
        int f = i * 256 + t; int row = f >> 3, c = f & 7;
        uint4 v = *(const uint4*)&Q[(size_t)(b * 2048 + qt * 128 + row) * 1024 + h * 64 + c * 8];
        *(uint4*)&Qs[row * 72 + c * 8] = v;
    }
    __syncthreads();   // Qs+mask ready; tile-0 DMA drained

    // hoist Q fragments; Qs LDS becomes Ps
    short8 qa[2][2];
#pragma unroll
    for (int st = 0; st < 2; ++st) {
        int qrow = w * 32 + st * 16 + l15;
        qa[st][0] = *(const short8*)&Qs[qrow * 72 + quad * 8];
        qa[st][1] = *(const short8*)&Qs[qrow * 72 + 32 + quad * 8];
    }
    unsigned short* Ps = Qs;

    float l_r[2][4], T_r[2][4];
    f32x4 o_acc[2][4];
#pragma unroll
    for (int st = 0; st < 2; ++st)
#pragma unroll
        for (int r = 0; r < 4; ++r) { l_r[st][r] = 0.f; T_r[st][r] = 0.f; }
#pragma unroll
    for (int st = 0; st < 2; ++st)
#pragma unroll
        for (int nt = 0; nt < 4; ++nt) o_acc[st][nt] = (f32x4){0.f, 0.f, 0.f, 0.f};

    for (int kt = 0; kt < 32; ++kt) {
        const int cur = kt & 1;
        // issue NEXT tile's DMA — the ONLY vmem in the loop; drains at the barrier
        if (kt < 31) {
            const int kn = (kt + 1) * 64;
            const int row0 = w * 16;
#pragma unroll
            for (int i = 0; i < 2; ++i) {
                int row = row0 + i * 8 + r8;
                int c = ch8 ^ (row & 7);
                glds16(&K[(size_t)(b * 2048 + kn + row) * 1024 + h * 64 + c * 8], &Ks[cur ^ 1][(row0 + i * 8) * 64]);
                glds16(&Vt[(size_t)(h * 64 + row) * 4096 + b * 2048 + kn + c * 8], &Vs[cur ^ 1][(row0 + i * 8) * 64]);
            }
        }

        // S = Q K^T (log2 domain): K frags shared across both q-subtiles
        f32x4 sacc[2][4];
#pragma unroll
        for (int st = 0; st < 2; ++st)
#pragma unroll
            for (int nt = 0; nt < 4; ++nt) sacc[st][nt] = (f32x4){0.f, 0.f, 0.f, 0.f};
#pragma unroll
        for (int nt = 0; nt < 4; ++nt) {
            int krow = nt * 16 + l15;
            short8 kf0 = *(const short8*)&Ks[cur][krow * 64 + ((quad ^ (krow & 7)) * 8)];
            short8 kf1 = *(const short8*)&Ks[cur][krow * 64 + (((quad + 4) ^ (krow & 7)) * 8)];
#pragma unroll
            for (int st = 0; st < 2; ++st) {
                sacc[st][nt] = __builtin_amdgcn_mfma_f32_16x16x32_bf16(qa[st][0], kf0, sacc[st][nt], 0, 0, 0);
                sacc[st][nt] = __builtin_amdgcn_mfma_f32_16x16x32_bf16(qa[st][1], kf1, sacc[st][nt], 0, 0, 0);
            }
        }
        int mk[4];
#pragma unroll
        for (int nt = 0; nt < 4; ++nt) mk[nt] = maskLds[kt * 64 + nt * 16 + l15];

        // no-max softmax (exp2) + P store (wave-local rows)
#pragma unroll
        for (int st = 0; st < 2; ++st) {
#pragma unroll
            for (int r = 0; r < 4; ++r) {
                float s0 = mk[0] ? sacc[st][0][r] : -1.0e30f;
                float s1 = mk[1] ? sacc[st][1][r] : -1.0e30f;
                float s2 = mk[2] ? sacc[st][2][r] : -1.0e30f;
                float s3 = mk[3] ? sacc[st][3][r] : -1.0e30f;
                float p0 = exp2f(s0), p1 = exp2f(s1), p2 = exp2f(s2), p3 = exp2f(s3);
                l_r[st][r] += (p0 + p1) + (p2 + p3);
                T_r[st][r] += (p0 * s0 + p1 * s1) + (p2 * s2 + p3 * s3);  // log2-domain
                int pbase = (w * 32 + st * 16 + quad * 4 + r) * 72 + l15;
                Ps[pbase]      = f2bf(p0);
                Ps[pbase + 16] = f2bf(p1);
                Ps[pbase + 32] = f2bf(p2);
                Ps[pbase + 48] = f2bf(p3);
            }
        }

        // O += P V : V frags shared across both q-subtiles
#pragma unroll
        for (int ks = 0; ks < 2; ++ks) {
            short8 pa[2];
#pragma unroll
            for (int st = 0; st < 2; ++st)
                pa[st] = *(const short8*)&Ps[(w * 32 + st * 16 + l15) * 72 + ks * 32 + quad * 8];
#pragma unroll
            for (int nt = 0; nt < 4; ++nt) {
                int vrow = nt * 16 + l15;
                short8 vf = *(const short8*)&Vs[cur][vrow * 64 + ((((ks * 4 + quad)) ^ (vrow & 7)) * 8)];
#pragma unroll
                for (int st = 0; st < 2; ++st)
                    o_acc[st][nt] = __builtin_amdgcn_mfma_f32_16x16x32_bf16(pa[st], vf, o_acc[st][nt], 0, 0, 0);
            }
        }
        __syncthreads();  // all waves done reading buf[cur]; own next-tile DMA drained
    }

    // finalize: reduce l,T across 16 lanes per q-row; write O; entropy
    float entacc = 0.f;
#pragma unroll
    for (int st = 0; st < 2; ++st) {
#pragma unroll
        for (int r = 0; r < 4; ++r) {
            float l = l_r[st][r], T = T_r[st][r];
            l += __shfl_xor(l, 1); T += __shfl_xor(T, 1);
            l += __shfl_xor(l, 2); T += __shfl_xor(T, 2);
            l += __shfl_xor(l, 4); T += __shfl_xor(T, 4);
            l += __shfl_xor(l, 8); T += __shfl_xor(T, 8);
            float inv = 1.0f / l;
            float ent = LN2 * (__log2f(l) - T * inv);   // -sum p log p (natural)
            if (l15 == 0) entacc += ent;
            int mrow = b * 2048 + qt * 128 + w * 32 + st * 16 + quad * 4 + r;
#pragma unroll
            for (int nt = 0; nt < 4; ++nt)
                O[(size_t)mrow * 1024 + h * 64 + nt * 16 + l15] = f2bf(o_acc[st][nt][r] * inv);
        }
    }
    entacc += __shfl_xor(entacc, 1);
    entacc += __shfl_xor(entacc, 2);
    entacc += __shfl_xor(entacc, 4);
    entacc += __shfl_xor(entacc, 8);
    entacc += __shfl_xor(entacc, 16);
    entacc += __shfl_xor(entacc, 32);
    if (lane == 0) atomicAdd(entp, entacc);
}

// ---------------------------------------------------------------------------
// Output GEMM bf16: out = scale_ent * (O @ ow.T) + ob, fp32 out. 128x64 tiles.
// ---------------------------------------------------------------------------
__global__ __launch_bounds__(256) void gemm_out_bf(
    const unsigned short* __restrict__ A, const unsigned short* __restrict__ Bw,
    const float* __restrict__ bias, const float* __restrict__ entp,
    float* __restrict__ C)
{
    const float avg = entp[0] * (1.0f / 65536.0f);
    const float scale = (avg < 0.2f) ? 1.0f : BLEND_C;

    const int m0 = blockIdx.x * 128;
    const int n0 = blockIdx.y * 64;
    __shared__ unsigned short As[128 * 32];
    __shared__ unsigned short Bs[64 * 32];
    const int t = threadIdx.x, lane = t & 63, w = t >> 6;
    const int quad = lane >> 4, l15 = lane & 15;
    const int wr = (w >> 1) * 64, wc = (w & 1) * 32;
    const int srow = lane >> 2, scol = (lane & 3) * 8;

    f32x4 acc[4][2];
#pragma unroll
    for (int i = 0; i < 4; ++i)
#pragma unroll
        for (int j = 0; j < 2; ++j) acc[i][j] = (f32x4){0.f, 0.f, 0.f, 0.f};

    for (int kk = 0; kk < 32; ++kk) {
        const int k0 = kk * 32;
#pragma unroll
        for (int j = 0; j < 2; ++j) {
            int row = (w * 2 + j) * 16 + srow;
            glds16(&A[(size_t)(m0 + row) * 1024 + k0 + scol], &As[(w * 2 + j) * 512]);
        }
        {
            int row = w * 16 + srow;
            glds16(&Bw[(size_t)(n0 + row) * 1024 + k0 + scol], &Bs[w * 512]);
        }
        __syncthreads();
        short8 af[4], bf[2];
#pragma unroll
        for (int mt = 0; mt < 4; ++mt) af[mt] = *(const short8*)&As[(wr + mt * 16 + l15) * 32 + quad * 8];
#pragma unroll
        for (int nt = 0; nt < 2; ++nt) bf[nt] = *(const short8*)&Bs[(wc + nt * 16 + l15) * 32 + quad * 8];
#pragma unroll
        for (int mt = 0; mt < 4; ++mt)
#pragma unroll
            for (int nt = 0; nt < 2; ++nt)
                acc[mt][nt] = __builtin_amdgcn_mfma_f32_16x16x32_bf16(af[mt], bf[nt], acc[mt][nt], 0, 0, 0);
        __syncthreads();
    }
#pragma unroll
    for (int mt = 0; mt < 4; ++mt) {
#pragma unroll
        for (int nt = 0; nt < 2; ++nt) {
            int n = n0 + wc + nt * 16 + l15;
#pragma unroll
            for (int r = 0; r < 4; ++r) {
                int m = m0 + wr + mt * 16 + quad * 4 + r;
                C[(size_t)m * 1024 + n] = scale * acc[mt][nt][r] + bias[n];
            }
        }
    }
}

// ---------------------------------------------------------------------------
// Fallback kernels (round-2 proven): fp32-staged GEMMs.
// ---------------------------------------------------------------------------
__global__ __launch_bounds__(256) void gemm_nt_f32(
    const float* __restrict__ A, const float* __restrict__ B,
    const float* __restrict__ bias, int biasRow, float scale,
    unsigned short* __restrict__ C, int N)
{
    const int m0 = blockIdx.x * 128;
    const int n0 = blockIdx.y * 128;
    __shared__ unsigned short As[128 * 40];
    __shared__ unsigned short Bs[128 * 40];
    const int t = threadIdx.x, lane = t & 63, w = t >> 6;
    const int wr = (w >> 1) * 64, wc = (w & 1) * 64;
    const int quad = lane >> 4, l15 = lane & 15;

    f32x4 acc[4][4];
#pragma unroll
    for (int i = 0; i < 4; ++i)
#pragma unroll
        for (int j = 0; j < 4; ++j) acc[i][j] = (f32x4){0.f, 0.f, 0.f, 0.f};

    for (int kk = 0; kk < 32; ++kk) {
        const int k0 = kk * 32;
#pragma unroll
        for (int i = 0; i < 4; ++i) {
            int f = i * 256 + t;
            int row = f >> 3, ch = f & 7;
            float4 av = *(const float4*)&A[(size_t)(m0 + row) * 1024 + k0 + ch * 4];
            ushort4 ap; ap.x = f2bf(av.x); ap.y = f2bf(av.y); ap.z = f2bf(av.z); ap.w = f2bf(av.w);
            *(ushort4*)&As[row * 40 + ch * 4] = ap;
            float4 bv = *(const float4*)&B[(size_t)(n0 + row) * 1024 + k0 + ch * 4];
            ushort4 bp; bp.x = f2bf(bv.x); bp.y = f2bf(bv.y); bp.z = f2bf(bv.z); bp.w = f2bf(bv.w);
            *(ushort4*)&Bs[row * 40 + ch * 4] = bp;
        }
        __syncthreads();
        short8 af[4], bfr[4];
#pragma unroll
        for (int mt = 0; mt < 4; ++mt) af[mt] = *(const short8*)&As[(wr + mt * 16 + l15) * 40 + quad * 8];
#pragma unroll
        for (int nt = 0; nt < 4; ++nt) bfr[nt] = *(const short8*)&Bs[(wc + nt * 16 + l15) * 40 + quad * 8];
#pragma unroll
        for (int mt = 0; mt < 4; ++mt)
#pragma unroll
            for (int nt = 0; nt < 4; ++nt)
                acc[mt][nt] = __builtin_amdgcn_mfma_f32_16x16x32_bf16(af[mt], bfr[nt], acc[mt][nt], 0, 0, 0);
        __syncthreads();
    }
#pragma unroll
    for (int mt = 0; mt < 4; ++mt) {
#pragma unroll
        for (int nt = 0; nt < 4; ++nt) {
            int n = n0 + wc + nt * 16 + l15;
#pragma unroll
            for (int r = 0; r < 4; ++r) {
                int m = m0 + wr + mt * 16 + quad * 4 + r;
                float bval = biasRow ? bias[m] : bias[n];
                C[(size_t)m * N + n] = f2bf((acc[mt][nt][r] + bval) * scale);
            }
        }
    }
}

__global__ __launch_bounds__(256) void gemm_out_f32B(
    const unsigned short* __restrict__ A, const float* __restrict__ B,
    const float* __restrict__ bias, const float* __restrict__ entp,
    float* __restrict__ C)
{
    const float avg = entp[0] * (1.0f / 65536.0f);
    const float scale = (avg < 0.2f) ? 1.0f : BLEND_C;

    const int m0 = blockIdx.x * 128;
    const int n0 = blockIdx.y * 128;
    __shared__ unsigned short As[128 * 40];
    __shared__ unsigned short Bs[128 * 40];
    const int t = threadIdx.x, lane = t & 63, w = t >> 6;
    const int wr = (w >> 1) * 64, wc = (w & 1) * 64;
    const int quad = lane >> 4, l15 = lane & 15;

    f32x4 acc[4][4];
#pragma unroll
    for (int i = 0; i < 4; ++i)
#pragma unroll
        for (int j = 0; j < 4; ++j) acc[i][j] = (f32x4){0.f, 0.f, 0.f, 0.f};

    for (int kk = 0; kk < 32; ++kk) {
        const int k0 = kk * 32;
#pragma unroll
        for (int i = 0; i < 2; ++i) {
            int f = i * 256 + t;
            int row = f >> 2, ch = f & 3;
            uint4 av = *(const uint4*)&A[(size_t)(m0 + row) * 1024 + k0 + ch * 8];
            *(uint4*)&As[row * 40 + ch * 8] = av;
        }
#pragma unroll
        for (int i = 0; i < 4; ++i) {
            int f = i * 256 + t;
            int row = f >> 3, ch = f & 7;
            float4 bv = *(const float4*)&B[(size_t)(n0 + row) * 1024 + k0 + ch * 4];
            ushort4 bp; bp.x = f2bf(bv.x); bp.y = f2bf(bv.y); bp.z = f2bf(bv.z); bp.w = f2bf(bv.w);
            *(ushort4*)&Bs[row * 40 + ch * 4] = bp;
        }
        __syncthreads();
        short8 af[4], bfr[4];
#pragma unroll
        for (int mt = 0; mt < 4; ++mt) af[mt] = *(const short8*)&As[(wr + mt * 16 + l15) * 40 + quad * 8];
#pragma unroll
        for (int nt = 0; nt < 4; ++nt) bfr[nt] = *(const short8*)&Bs[(wc + nt * 16 + l15) * 40 + quad * 8];
#pragma unroll
        for (int mt = 0; mt < 4; ++mt)
#pragma unroll
            for (int nt = 0; nt < 4; ++nt)
                acc[mt][nt] = __builtin_amdgcn_mfma_f32_16x16x32_bf16(af[mt], bfr[nt], acc[mt][nt], 0, 0, 0);
        __syncthreads();
    }
#pragma unroll
    for (int mt = 0; mt < 4; ++mt) {
#pragma unroll
        for (int nt = 0; nt < 4; ++nt) {
            int n = n0 + wc + nt * 16 + l15;
#pragma unroll
            for (int r = 0; r < 4; ++r) {
                int m = m0 + wr + mt * 16 + quad * 4 + r;
                C[(size_t)m * 1024 + n] = scale * acc[mt][nt][r] + bias[n];
            }
        }
    }
}

extern "C" void kernel_launch(void* const* d_in, const int* in_sizes, int n_in,
                              void* d_out, int out_size, void* d_ws, size_t ws_size,
                              hipStream_t stream)
{
    const float* hs = (const float*)d_in[0];
    const float* qw = (const float*)d_in[1];
    const float* qb = (const float*)d_in[2];
    const float* kw = (const float*)d_in[3];
    const float* kb = (const float*)d_in[4];
    const float* vw = (const float*)d_in[5];
    const float* vb = (const float*)d_in[6];
    const float* ow = (const float*)d_in[7];
    const float* ob = (const float*)d_in[8];
    const int*   mask = (const int*)d_in[9];
    float* out = (float*)d_out;

    const size_t MB = 1024 * 1024;
    char* ws = (char*)d_ws;
    dim3 blk(256);

    if (ws_size >= 40 * MB + 4) {
        // primary path
        unsigned short* hsb = (unsigned short*)(ws);            // 8MB; reused as O by flash
        unsigned short* Q   = (unsigned short*)(ws + 8 * MB);
        unsigned short* Kp  = (unsigned short*)(ws + 16 * MB);
        unsigned short* Vt  = (unsigned short*)(ws + 24 * MB);
        unsigned short* qwb = (unsigned short*)(ws + 32 * MB);
        unsigned short* kwb = (unsigned short*)(ws + 34 * MB);
        unsigned short* vwb = (unsigned short*)(ws + 36 * MB);
        unsigned short* owb = (unsigned short*)(ws + 38 * MB);
        float* entp         = (float*)(ws + 40 * MB);
        unsigned short* O   = hsb;  // hs_bf dead after gemm_qkv

        cvt5<<<dim3(8192), blk, 0, stream>>>(hs, qw, kw, vw, ow, hsb, qwb, kwb, vwb, owb, entp);
        gemm_qkv<<<dim3(768), blk, 0, stream>>>(hsb, qwb, kwb, vwb, qb, kb, vb, Q, Kp, Vt);
        flash_attn<<<dim3(16, 32), blk, 0, stream>>>(Q, Kp, Vt, mask, O, entp);
        gemm_out_bf<<<dim3(32, 16), blk, 0, stream>>>(O, owb, ob, entp, out);
    } else if (ws_size >= 32 * MB + 4) {
        // fallback: round-2 proven GEMMs + new flash (Q scaled to log2 domain)
        unsigned short* Q  = (unsigned short*)(ws);
        unsigned short* Kp = (unsigned short*)(ws + 8 * MB);
        unsigned short* Vt = (unsigned short*)(ws + 16 * MB);
        unsigned short* O  = (unsigned short*)(ws + 24 * MB);
        float* entp        = (float*)(ws + 32 * MB);

        zero_ent<<<dim3(1), dim3(1), 0, stream>>>(entp);
        gemm_nt_f32<<<dim3(32, 8), blk, 0, stream>>>(hs, qw, qb, 0, QSCALE, Q, 1024);
        gemm_nt_f32<<<dim3(32, 8), blk, 0, stream>>>(hs, kw, kb, 0, 1.0f, Kp, 1024);
        gemm_nt_f32<<<dim3(8, 32), blk, 0, stream>>>(vw, hs, vb, 1, 1.0f, Vt, 4096);
        flash_attn<<<dim3(16, 32), blk, 0, stream>>>(Q, Kp, Vt, mask, O, entp);
        gemm_out_f32B<<<dim3(32, 8), blk, 0, stream>>>(O, ow, ob, entp, out);
    } else {
        // diagnostic: clean zero output instead of OOB fault
        zero_out_f32<<<dim3((out_size + 255) / 256), blk, 0, stream>>>(out, out_size);
    }
}

// Round 6
// 227.215 us; speedup vs baseline: 1.0902x; 1.0902x over previous
//
#include <hip/hip_runtime.h>
#include <hip/hip_bf16.h>
#include <stdint.h>

// ResonanceAttention on MI355X (gfx950) — round 6.
// R5 post-mortem: exp2f() is libm (range fixups: VGPR 68->116, VALUBusy up) —
// NOT a bare v_exp_f32. R6: __builtin_amdgcn_exp2f (raw v_exp), fast 2-op bf16
// pack (round-half-up) for P/O stores. Rest identical to R5 (mask in LDS,
// glds16 double-buffered K/V, 128-row q-tiles, one barrier/tile).
// Pipeline: cvt5 -> gemm_qkv (fused Q/K/Vt) -> flash_attn -> gemm_out_bf.
// Blend loop folds to scale C=0.8509655 iff avg_entropy >= 0.2 (device-computed).

#define PRIME_SCALE 0.047245559126654356f  // 1/sqrt(7*64)
#define LOG2E       1.4426950408889634f
#define LN2         0.6931471805599453f
#define QSCALE      (PRIME_SCALE * LOG2E)  // Q pre-scaled so softmax uses exp2
#define BLEND_C     0.85096556f            // closed form of the MAX_ITERS recurrence

#if __has_builtin(__builtin_amdgcn_exp2f)
#define EXP2(x) __builtin_amdgcn_exp2f(x)   // raw v_exp_f32 (1 ulp), no libm fixups
#else
#define EXP2(x) exp2f(x)
#endif

typedef __attribute__((ext_vector_type(8))) short short8;
typedef __attribute__((ext_vector_type(4))) float f32x4;

__device__ __forceinline__ unsigned short f2bf(float x) {       // RNE (GEMM epilogues)
    union { float f; unsigned int u; } v; v.f = x;
    unsigned int r = (v.u + 0x7fffu + ((v.u >> 16) & 1u)) >> 16;
    return (unsigned short)r;
}
__device__ __forceinline__ unsigned short f2bf_fast(float x) {  // round-half-up, 2 ops
    union { float f; unsigned int u; } v; v.f = x;
    return (unsigned short)((v.u + 0x8000u) >> 16);
}

// async global->LDS, 16B per lane; LDS dest = wave-uniform base + lane*16 [m97]
__device__ __forceinline__ void glds16(const unsigned short* g, unsigned short* l) {
    __builtin_amdgcn_global_load_lds((const __attribute__((address_space(1))) unsigned int*)g,
                                     (__attribute__((address_space(3))) unsigned int*)l,
                                     16, 0, 0);
}
__device__ __forceinline__ void glds16i(const int* g, int* l) {
    __builtin_amdgcn_global_load_lds((const __attribute__((address_space(1))) unsigned int*)g,
                                     (__attribute__((address_space(3))) unsigned int*)l,
                                     16, 0, 0);
}

__global__ void zero_ent(float* p) { p[0] = 0.f; }

__global__ void zero_out_f32(float* p, int n) {
    int i = blockIdx.x * 256 + threadIdx.x;
    if (i < n) p[i] = 0.f;
}

// ---------------------------------------------------------------------------
// cvt5: fp32 -> bf16 for hs (4M elems) + qw/kw/vw/ow (1M each). Zeros entp.
// ---------------------------------------------------------------------------
__global__ __launch_bounds__(256) void cvt5(
    const float* __restrict__ s0, const float* __restrict__ s1, const float* __restrict__ s2,
    const float* __restrict__ s3, const float* __restrict__ s4,
    unsigned short* __restrict__ d0, unsigned short* __restrict__ d1, unsigned short* __restrict__ d2,
    unsigned short* __restrict__ d3, unsigned short* __restrict__ d4, float* entp)
{
    if (blockIdx.x == 0 && threadIdx.x == 0) entp[0] = 0.f;
    unsigned int i = blockIdx.x * 256 + threadIdx.x;   // float4 group index, total 2^21
    const float* s; unsigned short* d; unsigned int off;
    if (i < (1u << 20)) { s = s0; d = d0; off = i; }
    else {
        unsigned int j = i - (1u << 20);
        unsigned int sel = j >> 18; off = j & 0x3FFFFu;
        s = sel == 0 ? s1 : sel == 1 ? s2 : sel == 2 ? s3 : s4;
        d = sel == 0 ? d1 : sel == 1 ? d2 : sel == 2 ? d3 : d4;
    }
    float4 v = ((const float4*)s)[off];
    ushort4 p; p.x = f2bf(v.x); p.y = f2bf(v.y); p.z = f2bf(v.z); p.w = f2bf(v.w);
    ((ushort4*)d)[off] = p;
}

// ---------------------------------------------------------------------------
// Fused Q/K/Vt GEMM, bf16 in -> bf16 out, global_load_lds staging (m97 structure).
// 768 blocks: op0=Q (hs@qw.T+qb)*QSCALE (log2-domain), op1=K, op2=Vt (operand swap).
// ---------------------------------------------------------------------------
__global__ __launch_bounds__(256) void gemm_qkv(
    const unsigned short* __restrict__ hsb,
    const unsigned short* __restrict__ qwb, const unsigned short* __restrict__ kwb,
    const unsigned short* __restrict__ vwb,
    const float* __restrict__ qb, const float* __restrict__ kb, const float* __restrict__ vb,
    unsigned short* __restrict__ Qo, unsigned short* __restrict__ Ko, unsigned short* __restrict__ Vto)
{
    const int bid = blockIdx.x;
    const int op = bid >> 8, local = bid & 255;
    const unsigned short *A, *B; const float* bias; unsigned short* C;
    int m0, n0, ldc, biasRow; float scale;
    if (op == 0)      { A = hsb; B = qwb; bias = qb; C = Qo;  m0 = (local >> 3) * 128; n0 = (local & 7) * 128;  ldc = 1024; biasRow = 0; scale = QSCALE; }
    else if (op == 1) { A = hsb; B = kwb; bias = kb; C = Ko;  m0 = (local >> 3) * 128; n0 = (local & 7) * 128;  ldc = 1024; biasRow = 0; scale = 1.f; }
    else              { A = vwb; B = hsb; bias = vb; C = Vto; m0 = (local >> 5) * 128; n0 = (local & 31) * 128; ldc = 4096; biasRow = 1; scale = 1.f; }

    __shared__ unsigned short As[128 * 32];
    __shared__ unsigned short Bs[128 * 32];
    const int t = threadIdx.x, lane = t & 63, w = t >> 6;
    const int quad = lane >> 4, l15 = lane & 15;
    const int wr = (w >> 1) * 64, wc = (w & 1) * 64;
    const int srow = lane >> 2, scol = (lane & 3) * 8;

    f32x4 acc[4][4];
#pragma unroll
    for (int i = 0; i < 4; ++i)
#pragma unroll
        for (int j = 0; j < 4; ++j) acc[i][j] = (f32x4){0.f, 0.f, 0.f, 0.f};

    for (int kk = 0; kk < 32; ++kk) {
        const int k0 = kk * 32;
#pragma unroll
        for (int j = 0; j < 2; ++j) {
            int row = (w * 2 + j) * 16 + srow;
            glds16(&A[(size_t)(m0 + row) * 1024 + k0 + scol], &As[(w * 2 + j) * 512]);
            glds16(&B[(size_t)(n0 + row) * 1024 + k0 + scol], &Bs[(w * 2 + j) * 512]);
        }
        __syncthreads();
        short8 af[4], bf[4];
#pragma unroll
        for (int mt = 0; mt < 4; ++mt) af[mt] = *(const short8*)&As[(wr + mt * 16 + l15) * 32 + quad * 8];
#pragma unroll
        for (int nt = 0; nt < 4; ++nt) bf[nt] = *(const short8*)&Bs[(wc + nt * 16 + l15) * 32 + quad * 8];
#pragma unroll
        for (int mt = 0; mt < 4; ++mt)
#pragma unroll
            for (int nt = 0; nt < 4; ++nt)
                acc[mt][nt] = __builtin_amdgcn_mfma_f32_16x16x32_bf16(af[mt], bf[nt], acc[mt][nt], 0, 0, 0);
        __syncthreads();
    }
#pragma unroll
    for (int mt = 0; mt < 4; ++mt) {
#pragma unroll
        for (int nt = 0; nt < 4; ++nt) {
            int n = n0 + wc + nt * 16 + l15;
#pragma unroll
            for (int r = 0; r < 4; ++r) {
                int m = m0 + wr + mt * 16 + quad * 4 + r;
                float bval = biasRow ? bias[m] : bias[n];
                C[(size_t)m * ldc + n] = f2bf((acc[mt][nt][r] + bval) * scale);
            }
        }
    }
}

// ---------------------------------------------------------------------------
// Flash attention r6: 128 q-rows/block (32/wave), glds16 K/V staging w/ global-
// side XOR swizzle, double-buffered, ONE barrier/tile, mask row in LDS.
// Softmax in exp2 domain via raw v_exp_f32; P/O stored with 2-op bf16 pack.
// Entropy = ln2*(log2 l - T2/l), T2 = sum p * log2 p-domain score.
// ---------------------------------------------------------------------------
__global__ __launch_bounds__(256, 2) void flash_attn(
    const unsigned short* __restrict__ Q,
    const unsigned short* __restrict__ K,
    const unsigned short* __restrict__ Vt,
    const int* __restrict__ mask,
    unsigned short* __restrict__ O,
    float* __restrict__ entp)
{
    const int qt = blockIdx.x;          // 0..15, 128 q-rows each
    const int bh = blockIdx.y;          // 0..31
    const int b = bh >> 4, h = bh & 15;
    const int t = threadIdx.x, lane = t & 63, w = t >> 6;
    const int quad = lane >> 4, l15 = lane & 15;
    const int r8 = lane >> 3, ch8 = lane & 7;   // staging row-in-8 / chunk

    __shared__ unsigned short Qs[128 * 72];      // Q staged once; reused as Ps
    __shared__ unsigned short Ks[2][64 * 64];    // [k-row][d], chunk swizzled by row&7
    __shared__ unsigned short Vs[2][64 * 64];    // [d-row][k], chunk swizzled by row&7
    __shared__ int maskLds[2048];                // whole mask row for batch b

    const int* maskb = mask + b * 2048;
    // stage mask row once: 8 chunks x 256 ints, wave w does chunks {w, w+4}
#pragma unroll
    for (int i = 0; i < 2; ++i) {
        int c = w + i * 4;
        glds16i(&maskb[c * 256 + (lane << 2)], &maskLds[c * 256]);
    }
    // issue tile-0 K/V DMA (wave w stages rows w*16..w*16+15; 8 rows per glds16)
    {
        const int row0 = w * 16;
#pragma unroll
        for (int i = 0; i < 2; ++i) {
            int row = row0 + i * 8 + r8;
            int c = ch8 ^ (row & 7);           // global-side swizzle, same 128B lines
            glds16(&K[(size_t)(b * 2048 + row) * 1024 + h * 64 + c * 8], &Ks[0][(row0 + i * 8) * 64]);
            glds16(&Vt[(size_t)(h * 64 + row) * 4096 + b * 2048 + c * 8], &Vs[0][(row0 + i * 8) * 64]);
        }
    }
    // stage Q tile (once)
#pragma unroll
    for (int i = 0; i < 4; ++i) {
        int f = i * 256 + t; int row = f >> 3, c = f & 7;
        uint4 v = *(const uint4*)&Q[(size_t)(b * 2048 + qt * 128 + row) * 1024 + h * 64 + c * 8];
        *(uint4*)&Qs[row * 72 + c * 8] = v;
    }
    __syncthreads();   // Qs+mask ready; tile-0 DMA drained

    // hoist Q fragments; Qs LDS becomes Ps
    short8 qa[2][2];
#pragma unroll
    for (int st = 0; st < 2; ++st) {
        int qrow = w * 32 + st * 16 + l15;
        qa[st][0] = *(const short8*)&Qs[qrow * 72 + quad * 8];
        qa[st][1] = *(const short8*)&Qs[qrow * 72 + 32 + quad * 8];
    }
    unsigned short* Ps = Qs;

    float l_r[2][4], T_r[2][4];
    f32x4 o_acc[2][4];
#pragma unroll
    for (int st = 0; st < 2; ++st)
#pragma unroll
        for (int r = 0; r < 4; ++r) { l_r[st][r] = 0.f; T_r[st][r] = 0.f; }
#pragma unroll
    for (int st = 0; st < 2; ++st)
#pragma unroll
        for (int nt = 0; nt < 4; ++nt) o_acc[st][nt] = (f32x4){0.f, 0.f, 0.f, 0.f};

    for (int kt = 0; kt < 32; ++kt) {
        const int cur = kt & 1;
        // issue NEXT tile's DMA — the ONLY vmem in the loop; drains at the barrier
        if (kt < 31) {
            const int kn = (kt + 1) * 64;
            const int row0 = w * 16;
#pragma unroll
            for (int i = 0; i < 2; ++i) {
                int row = row0 + i * 8 + r8;
                int c = ch8 ^ (row & 7);
                glds16(&K[(size_t)(b * 2048 + kn + row) * 1024 + h * 64 + c * 8], &Ks[cur ^ 1][(row0 + i * 8) * 64]);
                glds16(&Vt[(size_t)(h * 64 + row) * 4096 + b * 2048 + kn + c * 8], &Vs[cur ^ 1][(row0 + i * 8) * 64]);
            }
        }

        // S = Q K^T (log2 domain): K frags shared across both q-subtiles
        f32x4 sacc[2][4];
#pragma unroll
        for (int st = 0; st < 2; ++st)
#pragma unroll
            for (int nt = 0; nt < 4; ++nt) sacc[st][nt] = (f32x4){0.f, 0.f, 0.f, 0.f};
#pragma unroll
        for (int nt = 0; nt < 4; ++nt) {
            int krow = nt * 16 + l15;
            short8 kf0 = *(const short8*)&Ks[cur][krow * 64 + ((quad ^ (krow & 7)) * 8)];
            short8 kf1 = *(const short8*)&Ks[cur][krow * 64 + (((quad + 4) ^ (krow & 7)) * 8)];
#pragma unroll
            for (int st = 0; st < 2; ++st) {
                sacc[st][nt] = __builtin_amdgcn_mfma_f32_16x16x32_bf16(qa[st][0], kf0, sacc[st][nt], 0, 0, 0);
                sacc[st][nt] = __builtin_amdgcn_mfma_f32_16x16x32_bf16(qa[st][1], kf1, sacc[st][nt], 0, 0, 0);
            }
        }
        int mk[4];
#pragma unroll
        for (int nt = 0; nt < 4; ++nt) mk[nt] = maskLds[kt * 64 + nt * 16 + l15];

        // no-max softmax (raw v_exp_f32) + packed P store (wave-local rows)
#pragma unroll
        for (int st = 0; st < 2; ++st) {
#pragma unroll
            for (int r = 0; r < 4; ++r) {
                float s0 = mk[0] ? sacc[st][0][r] : -1.0e30f;
                float s1 = mk[1] ? sacc[st][1][r] : -1.0e30f;
                float s2 = mk[2] ? sacc[st][2][r] : -1.0e30f;
                float s3 = mk[3] ? sacc[st][3][r] : -1.0e30f;
                float p0 = EXP2(s0), p1 = EXP2(s1), p2 = EXP2(s2), p3 = EXP2(s3);
                l_r[st][r] += (p0 + p1) + (p2 + p3);
                T_r[st][r] += (p0 * s0 + p1 * s1) + (p2 * s2 + p3 * s3);  // log2-domain
                int pbase = (w * 32 + st * 16 + quad * 4 + r) * 72 + l15;
                Ps[pbase]      = f2bf_fast(p0);
                Ps[pbase + 16] = f2bf_fast(p1);
                Ps[pbase + 32] = f2bf_fast(p2);
                Ps[pbase + 48] = f2bf_fast(p3);
            }
        }

        // O += P V : V frags shared across both q-subtiles
#pragma unroll
        for (int ks = 0; ks < 2; ++ks) {
            short8 pa[2];
#pragma unroll
            for (int st = 0; st < 2; ++st)
                pa[st] = *(const short8*)&Ps[(w * 32 + st * 16 + l15) * 72 + ks * 32 + quad * 8];
#pragma unroll
            for (int nt = 0; nt < 4; ++nt) {
                int vrow = nt * 16 + l15;
                short8 vf = *(const short8*)&Vs[cur][vrow * 64 + ((((ks * 4 + quad)) ^ (vrow & 7)) * 8)];
#pragma unroll
                for (int st = 0; st < 2; ++st)
                    o_acc[st][nt] = __builtin_amdgcn_mfma_f32_16x16x32_bf16(pa[st], vf, o_acc[st][nt], 0, 0, 0);
            }
        }
        __syncthreads();  // all waves done reading buf[cur]; own next-tile DMA drained
    }

    // finalize: reduce l,T across 16 lanes per q-row; write O; entropy
    float entacc = 0.f;
#pragma unroll
    for (int st = 0; st < 2; ++st) {
#pragma unroll
        for (int r = 0; r < 4; ++r) {
            float l = l_r[st][r], T = T_r[st][r];
            l += __shfl_xor(l, 1); T += __shfl_xor(T, 1);
            l += __shfl_xor(l, 2); T += __shfl_xor(T, 2);
            l += __shfl_xor(l, 4); T += __shfl_xor(T, 4);
            l += __shfl_xor(l, 8); T += __shfl_xor(T, 8);
            float inv = 1.0f / l;
            float ent = LN2 * (__log2f(l) - T * inv);   // -sum p log p (natural)
            if (l15 == 0) entacc += ent;
            int mrow = b * 2048 + qt * 128 + w * 32 + st * 16 + quad * 4 + r;
#pragma unroll
            for (int nt = 0; nt < 4; ++nt)
                O[(size_t)mrow * 1024 + h * 64 + nt * 16 + l15] = f2bf_fast(o_acc[st][nt][r] * inv);
        }
    }
    entacc += __shfl_xor(entacc, 1);
    entacc += __shfl_xor(entacc, 2);
    entacc += __shfl_xor(entacc, 4);
    entacc += __shfl_xor(entacc, 8);
    entacc += __shfl_xor(entacc, 16);
    entacc += __shfl_xor(entacc, 32);
    if (lane == 0) atomicAdd(entp, entacc);
}

// ---------------------------------------------------------------------------
// Output GEMM bf16: out = scale_ent * (O @ ow.T) + ob, fp32 out. 128x64 tiles.
// ---------------------------------------------------------------------------
__global__ __launch_bounds__(256) void gemm_out_bf(
    const unsigned short* __restrict__ A, const unsigned short* __restrict__ Bw,
    const float* __restrict__ bias, const float* __restrict__ entp,
    float* __restrict__ C)
{
    const float avg = entp[0] * (1.0f / 65536.0f);
    const float scale = (avg < 0.2f) ? 1.0f : BLEND_C;

    const int m0 = blockIdx.x * 128;
    const int n0 = blockIdx.y * 64;
    __shared__ unsigned short As[128 * 32];
    __shared__ unsigned short Bs[64 * 32];
    const int t = threadIdx.x, lane = t & 63, w = t >> 6;
    const int quad = lane >> 4, l15 = lane & 15;
    const int wr = (w >> 1) * 64, wc = (w & 1) * 32;
    const int srow = lane >> 2, scol = (lane & 3) * 8;

    f32x4 acc[4][2];
#pragma unroll
    for (int i = 0; i < 4; ++i)
#pragma unroll
        for (int j = 0; j < 2; ++j) acc[i][j] = (f32x4){0.f, 0.f, 0.f, 0.f};

    for (int kk = 0; kk < 32; ++kk) {
        const int k0 = kk * 32;
#pragma unroll
        for (int j = 0; j < 2; ++j) {
            int row = (w * 2 + j) * 16 + srow;
            glds16(&A[(size_t)(m0 + row) * 1024 + k0 + scol], &As[(w * 2 + j) * 512]);
        }
        {
            int row = w * 16 + srow;
            glds16(&Bw[(size_t)(n0 + row) * 1024 + k0 + scol], &Bs[w * 512]);
        }
        __syncthreads();
        short8 af[4], bf[2];
#pragma unroll
        for (int mt = 0; mt < 4; ++mt) af[mt] = *(const short8*)&As[(wr + mt * 16 + l15) * 32 + quad * 8];
#pragma unroll
        for (int nt = 0; nt < 2; ++nt) bf[nt] = *(const short8*)&Bs[(wc + nt * 16 + l15) * 32 + quad * 8];
#pragma unroll
        for (int mt = 0; mt < 4; ++mt)
#pragma unroll
            for (int nt = 0; nt < 2; ++nt)
                acc[mt][nt] = __builtin_amdgcn_mfma_f32_16x16x32_bf16(af[mt], bf[nt], acc[mt][nt], 0, 0, 0);
        __syncthreads();
    }
#pragma unroll
    for (int mt = 0; mt < 4; ++mt) {
#pragma unroll
        for (int nt = 0; nt < 2; ++nt) {
            int n = n0 + wc + nt * 16 + l15;
#pragma unroll
            for (int r = 0; r < 4; ++r) {
                int m = m0 + wr + mt * 16 + quad * 4 + r;
                C[(size_t)m * 1024 + n] = scale * acc[mt][nt][r] + bias[n];
            }
        }
    }
}

// ---------------------------------------------------------------------------
// Fallback kernels (round-2 proven): fp32-staged GEMMs.
// ---------------------------------------------------------------------------
__global__ __launch_bounds__(256) void gemm_nt_f32(
    const float* __restrict__ A, const float* __restrict__ B,
    const float* __restrict__ bias, int biasRow, float scale,
    unsigned short* __restrict__ C, int N)
{
    const int m0 = blockIdx.x * 128;
    const int n0 = blockIdx.y * 128;
    __shared__ unsigned short As[128 * 40];
    __shared__ unsigned short Bs[128 * 40];
    const int t = threadIdx.x, lane = t & 63, w = t >> 6;
    const int wr = (w >> 1) * 64, wc = (w & 1) * 64;
    const int quad = lane >> 4, l15 = lane & 15;

    f32x4 acc[4][4];
#pragma unroll
    for (int i = 0; i < 4; ++i)
#pragma unroll
        for (int j = 0; j < 4; ++j) acc[i][j] = (f32x4){0.f, 0.f, 0.f, 0.f};

    for (int kk = 0; kk < 32; ++kk) {
        const int k0 = kk * 32;
#pragma unroll
        for (int i = 0; i < 4; ++i) {
            int f = i * 256 + t;
            int row = f >> 3, ch = f & 7;
            float4 av = *(const float4*)&A[(size_t)(m0 + row) * 1024 + k0 + ch * 4];
            ushort4 ap; ap.x = f2bf(av.x); ap.y = f2bf(av.y); ap.z = f2bf(av.z); ap.w = f2bf(av.w);
            *(ushort4*)&As[row * 40 + ch * 4] = ap;
            float4 bv = *(const float4*)&B[(size_t)(n0 + row) * 1024 + k0 + ch * 4];
            ushort4 bp; bp.x = f2bf(bv.x); bp.y = f2bf(bv.y); bp.z = f2bf(bv.z); bp.w = f2bf(bv.w);
            *(ushort4*)&Bs[row * 40 + ch * 4] = bp;
        }
        __syncthreads();
        short8 af[4], bfr[4];
#pragma unroll
        for (int mt = 0; mt < 4; ++mt) af[mt] = *(const short8*)&As[(wr + mt * 16 + l15) * 40 + quad * 8];
#pragma unroll
        for (int nt = 0; nt < 4; ++nt) bfr[nt] = *(const short8*)&Bs[(wc + nt * 16 + l15) * 40 + quad * 8];
#pragma unroll
        for (int mt = 0; mt < 4; ++mt)
#pragma unroll
            for (int nt = 0; nt < 4; ++nt)
                acc[mt][nt] = __builtin_amdgcn_mfma_f32_16x16x32_bf16(af[mt], bfr[nt], acc[mt][nt], 0, 0, 0);
        __syncthreads();
    }
#pragma unroll
    for (int mt = 0; mt < 4; ++mt) {
#pragma unroll
        for (int nt = 0; nt < 4; ++nt) {
            int n = n0 + wc + nt * 16 + l15;
#pragma unroll
            for (int r = 0; r < 4; ++r) {
                int m = m0 + wr + mt * 16 + quad * 4 + r;
                float bval = biasRow ? bias[m] : bias[n];
                C[(size_t)m * N + n] = f2bf((acc[mt][nt][r] + bval) * scale);
            }
        }
    }
}

__global__ __launch_bounds__(256) void gemm_out_f32B(
    const unsigned short* __restrict__ A, const float* __restrict__ B,
    const float* __restrict__ bias, const float* __restrict__ entp,
    float* __restrict__ C)
{
    const float avg = entp[0] * (1.0f / 65536.0f);
    const float scale = (avg < 0.2f) ? 1.0f : BLEND_C;

    const int m0 = blockIdx.x * 128;
    const int n0 = blockIdx.y * 128;
    __shared__ unsigned short As[128 * 40];
    __shared__ unsigned short Bs[128 * 40];
    const int t = threadIdx.x, lane = t & 63, w = t >> 6;
    const int wr = (w >> 1) * 64, wc = (w & 1) * 64;
    const int quad = lane >> 4, l15 = lane & 15;

    f32x4 acc[4][4];
#pragma unroll
    for (int i = 0; i < 4; ++i)
#pragma unroll
        for (int j = 0; j < 4; ++j) acc[i][j] = (f32x4){0.f, 0.f, 0.f, 0.f};

    for (int kk = 0; kk < 32; ++kk) {
        const int k0 = kk * 32;
#pragma unroll
        for (int i = 0; i < 2; ++i) {
            int f = i * 256 + t;
            int row = f >> 2, ch = f & 3;
            uint4 av = *(const uint4*)&A[(size_t)(m0 + row) * 1024 + k0 + ch * 8];
            *(uint4*)&As[row * 40 + ch * 8] = av;
        }
#pragma unroll
        for (int i = 0; i < 4; ++i) {
            int f = i * 256 + t;
            int row = f >> 3, ch = f & 7;
            float4 bv = *(const float4*)&B[(size_t)(n0 + row) * 1024 + k0 + ch * 4];
            ushort4 bp; bp.x = f2bf(bv.x); bp.y = f2bf(bv.y); bp.z = f2bf(bv.z); bp.w = f2bf(bv.w);
            *(ushort4*)&Bs[row * 40 + ch * 4] = bp;
        }
        __syncthreads();
        short8 af[4], bfr[4];
#pragma unroll
        for (int mt = 0; mt < 4; ++mt) af[mt] = *(const short8*)&As[(wr + mt * 16 + l15) * 40 + quad * 8];
#pragma unroll
        for (int nt = 0; nt < 4; ++nt) bfr[nt] = *(const short8*)&Bs[(wc + nt * 16 + l15) * 40 + quad * 8];
#pragma unroll
        for (int mt = 0; mt < 4; ++mt)
#pragma unroll
            for (int nt = 0; nt < 4; ++nt)
                acc[mt][nt] = __builtin_amdgcn_mfma_f32_16x16x32_bf16(af[mt], bfr[nt], acc[mt][nt], 0, 0, 0);
        __syncthreads();
    }
#pragma unroll
    for (int mt = 0; mt < 4; ++mt) {
#pragma unroll
        for (int nt = 0; nt < 4; ++nt) {
            int n = n0 + wc + nt * 16 + l15;
#pragma unroll
            for (int r = 0; r < 4; ++r) {
                int m = m0 + wr + mt * 16 + quad * 4 + r;
                C[(size_t)m * 1024 + n] = scale * acc[mt][nt][r] + bias[n];
            }
        }
    }
}

extern "C" void kernel_launch(void* const* d_in, const int* in_sizes, int n_in,
                              void* d_out, int out_size, void* d_ws, size_t ws_size,
                              hipStream_t stream)
{
    const float* hs = (const float*)d_in[0];
    const float* qw = (const float*)d_in[1];
    const float* qb = (const float*)d_in[2];
    const float* kw = (const float*)d_in[3];
    const float* kb = (const float*)d_in[4];
    const float* vw = (const float*)d_in[5];
    const float* vb = (const float*)d_in[6];
    const float* ow = (const float*)d_in[7];
    const float* ob = (const float*)d_in[8];
    const int*   mask = (const int*)d_in[9];
    float* out = (float*)d_out;

    const size_t MB = 1024 * 1024;
    char* ws = (char*)d_ws;
    dim3 blk(256);

    if (ws_size >= 40 * MB + 4) {
        // primary path
        unsigned short* hsb = (unsigned short*)(ws);            // 8MB; reused as O by flash
        unsigned short* Q   = (unsigned short*)(ws + 8 * MB);
        unsigned short* Kp  = (unsigned short*)(ws + 16 * MB);
        unsigned short* Vt  = (unsigned short*)(ws + 24 * MB);
        unsigned short* qwb = (unsigned short*)(ws + 32 * MB);
        unsigned short* kwb = (unsigned short*)(ws + 34 * MB);
        unsigned short* vwb = (unsigned short*)(ws + 36 * MB);
        unsigned short* owb = (unsigned short*)(ws + 38 * MB);
        float* entp         = (float*)(ws + 40 * MB);
        unsigned short* O   = hsb;  // hs_bf dead after gemm_qkv

        cvt5<<<dim3(8192), blk, 0, stream>>>(hs, qw, kw, vw, ow, hsb, qwb, kwb, vwb, owb, entp);
        gemm_qkv<<<dim3(768), blk, 0, stream>>>(hsb, qwb, kwb, vwb, qb, kb, vb, Q, Kp, Vt);
        flash_attn<<<dim3(16, 32), blk, 0, stream>>>(Q, Kp, Vt, mask, O, entp);
        gemm_out_bf<<<dim3(32, 16), blk, 0, stream>>>(O, owb, ob, entp, out);
    } else if (ws_size >= 32 * MB + 4) {
        // fallback: round-2 proven GEMMs + new flash (Q scaled to log2 domain)
        unsigned short* Q  = (unsigned short*)(ws);
        unsigned short* Kp = (unsigned short*)(ws + 8 * MB);
        unsigned short* Vt = (unsigned short*)(ws + 16 * MB);
        unsigned short* O  = (unsigned short*)(ws + 24 * MB);
        float* entp        = (float*)(ws + 32 * MB);

        zero_ent<<<dim3(1), dim3(1), 0, stream>>>(entp);
        gemm_nt_f32<<<dim3(32, 8), blk, 0, stream>>>(hs, qw, qb, 0, QSCALE, Q, 1024);
        gemm_nt_f32<<<dim3(32, 8), blk, 0, stream>>>(hs, kw, kb, 0, 1.0f, Kp, 1024);
        gemm_nt_f32<<<dim3(8, 32), blk, 0, stream>>>(vw, hs, vb, 1, 1.0f, Vt, 4096);
        flash_attn<<<dim3(16, 32), blk, 0, stream>>>(Q, Kp, Vt, mask, O, entp);
        gemm_out_f32B<<<dim3(32, 8), blk, 0, stream>>>(O, ow, ob, entp, out);
    } else {
        // diagnostic: clean zero output instead of OOB fault
        zero_out_f32<<<dim3((out_size + 255) / 256), blk, 0, stream>>>(out, out_size);
    }
}